// Round 1
// baseline (626.742 us; speedup 1.0000x reference)
//
#include <hip/hip_runtime.h>

#define BT 16
#define NN 8192
#define FIN 128
#define FOUT 32
#define NB 512   // BT*FOUT

typedef __attribute__((ext_vector_type(8))) short short8;
typedef __attribute__((ext_vector_type(4))) float float4v;

__device__ __forceinline__ float bf2f(unsigned short u) {
    unsigned v = ((unsigned)u) << 16;
    float f;
    __builtin_memcpy(&f, &v, 4);
    return f;
}
__device__ __forceinline__ unsigned short f2bf(float f) {
    unsigned u;
    __builtin_memcpy(&u, &f, 4);
    u += 0x7FFFu + ((u >> 16) & 1u);   // RNE
    return (unsigned short)(u >> 16);
}

// ---------------------------------------------------------------------------
// Sniff: decide whether float tensors are bf16-packed or fp32.
// If data is bf16, the low 16 bits of each word are a bf16 value with sane
// magnitude; if fp32, they're mantissa noise -> wild exponents.
// ---------------------------------------------------------------------------
__global__ void sniff_dtype(const unsigned* __restrict__ Wraw, unsigned* __restrict__ flag) {
    int lane = threadIdx.x;  // 64 lanes
    unsigned u = Wraw[lane];
    float f = bf2f((unsigned short)(u & 0xFFFFu));
    float af = fabsf(f);
    bool plaus = (af > 1e-5f) && (af < 1e3f);
    unsigned long long m = __ballot(plaus);
    if (lane == 0) flag[0] = (__popcll(m) >= 32) ? 1u : 0u;
}

// ---------------------------------------------------------------------------
// K1: h = inp @ W  -> H_T bf16 [NB][NN]  (row bto = bt*32+o, col = node j)
// block: 256 thr, 256 nodes per block, grid (NN/256, BT)
// thread t: ng = t>>2 (4 nodes), og = t&3 (8 outputs)
// ---------------------------------------------------------------------------
__launch_bounds__(256)
__global__ void k1_h(const void* __restrict__ inp_raw, const void* __restrict__ W_raw,
                     unsigned short* __restrict__ Ht, const unsigned* __restrict__ flagp) {
    __shared__ float W_s[FIN * FOUT];      // 16 KB
    __shared__ float inp_s[256 * 33];      // 33792 B (33 = pad)
    const int tid = threadIdx.x;
    const int bt = blockIdx.y;
    const int n0 = blockIdx.x * 256;
    const bool isbf = (*flagp != 0u);

    // stage W -> fp32 LDS
    if (isbf) {
        const unsigned short* Wb = (const unsigned short*)W_raw;
        for (int r = 0; r < 2; ++r) {
            int g = tid + 256 * r;             // 512 groups of 8
            const unsigned short* src = Wb + g * 8;
            ushort4 a = *(const ushort4*)(src);
            ushort4 b = *(const ushort4*)(src + 4);
            float* dst = &W_s[g * 8];
            dst[0] = bf2f(a.x); dst[1] = bf2f(a.y); dst[2] = bf2f(a.z); dst[3] = bf2f(a.w);
            dst[4] = bf2f(b.x); dst[5] = bf2f(b.y); dst[6] = bf2f(b.z); dst[7] = bf2f(b.w);
        }
    } else {
        const float4* Wf = (const float4*)W_raw;
        for (int r = 0; r < 4; ++r) {
            int g = tid + 256 * r;             // 1024 float4
            ((float4*)W_s)[g] = Wf[g];
        }
    }

    const int ng = tid >> 2, og = tid & 3;
    float acc[4][8];
#pragma unroll
    for (int r = 0; r < 4; ++r)
#pragma unroll
        for (int c = 0; c < 8; ++c) acc[r][c] = 0.f;

    for (int chunk = 0; chunk < 4; ++chunk) {
        int ii0 = chunk * 32;
        __syncthreads();
        if (isbf) {
            const unsigned short* ib = (const unsigned short*)inp_raw + ((size_t)bt * NN + n0) * FIN;
            for (int r = 0; r < 4; ++r) {
                int g = tid + 256 * r;          // 1024 groups of 8
                int row = g >> 2, c8 = (g & 3) * 8;
                const unsigned short* src = ib + row * FIN + ii0 + c8;
                ushort4 a = *(const ushort4*)(src);
                ushort4 b = *(const ushort4*)(src + 4);
                float* dst = &inp_s[row * 33 + c8];
                dst[0] = bf2f(a.x); dst[1] = bf2f(a.y); dst[2] = bf2f(a.z); dst[3] = bf2f(a.w);
                dst[4] = bf2f(b.x); dst[5] = bf2f(b.y); dst[6] = bf2f(b.z); dst[7] = bf2f(b.w);
            }
        } else {
            const float* iff = (const float*)inp_raw + ((size_t)bt * NN + n0) * FIN;
            for (int r = 0; r < 8; ++r) {
                int g = tid + 256 * r;          // 2048 float4
                int row = g >> 3, c4 = (g & 7) * 4;
                float4 v = *(const float4*)(iff + row * FIN + ii0 + c4);
                float* dst = &inp_s[row * 33 + c4];
                dst[0] = v.x; dst[1] = v.y; dst[2] = v.z; dst[3] = v.w;
            }
        }
        __syncthreads();
#pragma unroll
        for (int ii = 0; ii < 32; ++ii) {
            int i = ii0 + ii;
            float4 w0 = *(const float4*)&W_s[i * FOUT + og * 8];
            float4 w1 = *(const float4*)&W_s[i * FOUT + og * 8 + 4];
            float wv[8] = {w0.x, w0.y, w0.z, w0.w, w1.x, w1.y, w1.z, w1.w};
            float x0 = inp_s[(ng * 4 + 0) * 33 + ii];
            float x1 = inp_s[(ng * 4 + 1) * 33 + ii];
            float x2 = inp_s[(ng * 4 + 2) * 33 + ii];
            float x3 = inp_s[(ng * 4 + 3) * 33 + ii];
#pragma unroll
            for (int c = 0; c < 8; ++c) {
                acc[0][c] += x0 * wv[c];
                acc[1][c] += x1 * wv[c];
                acc[2][c] += x2 * wv[c];
                acc[3][c] += x3 * wv[c];
            }
        }
    }

    __syncthreads();
    // transpose through LDS: Hs[32 o][264 n-padded] bf16 (aliases inp_s)
    unsigned short* Hs = (unsigned short*)inp_s;
#pragma unroll
    for (int c = 0; c < 8; ++c) {
        int o = og * 8 + c;
        ushort4 p;
        p.x = f2bf(acc[0][c]); p.y = f2bf(acc[1][c]);
        p.z = f2bf(acc[2][c]); p.w = f2bf(acc[3][c]);
        *(ushort4*)&Hs[o * 264 + ng * 4] = p;
    }
    __syncthreads();
    {
        int o = tid >> 3, s8 = tid & 7;
        unsigned short* dstrow = Ht + (size_t)(bt * FOUT + o) * NN + n0;
        for (int s2 = 0; s2 < 4; ++s2) {
            int seg = s8 + 8 * s2;
            int4 v = *(const int4*)&Hs[o * 264 + seg * 8];
            *(int4*)(dstrow + seg * 8) = v;
        }
    }
}

// ---------------------------------------------------------------------------
// K1b: sumh[r] = sum_j H_T[r][j]   (512 rows)
// ---------------------------------------------------------------------------
__launch_bounds__(256)
__global__ void k1b_sumh(const unsigned short* __restrict__ Ht, float* __restrict__ sumh) {
    int r = blockIdx.x;
    const int4* row = (const int4*)(Ht + (size_t)r * NN);  // 1024 chunks of 8 bf16
    int tid = threadIdx.x;
    float s = 0.f;
    for (int j = 0; j < 4; ++j) {
        int4 v = row[j * 256 + tid];
        const unsigned short* u = (const unsigned short*)&v;
#pragma unroll
        for (int e = 0; e < 8; ++e) s += bf2f(u[e]);
    }
    for (int off = 32; off > 0; off >>= 1) s += __shfl_down(s, off);
    __shared__ float wsum[4];
    int lane = tid & 63, w = tid >> 6;
    if (lane == 0) wsum[w] = s;
    __syncthreads();
    if (tid == 0) sumh[r] = wsum[0] + wsum[1] + wsum[2] + wsum[3];
}

// ---------------------------------------------------------------------------
// K2: nbr[i][bto] = sum_k mask(adj[k][i]) * H_T[bto][k]
// MFMA bf16 16x16x32, tile 128(i) x 128(bto), BK=64, 256 thr (4 waves).
// A staged transposed from adj with int->bf16(1.0) fused; B from H_T rows.
// grid (NB/128=4, NN/128=64): bto-tiles adjacent -> shared adj slice in L3.
// ---------------------------------------------------------------------------
#define BKK 64
#define PADK 72   // +8 bf16 row pad (16 B) -> conflict-optimal b128 access

__launch_bounds__(256)
__global__ void k2_gemm(const int* __restrict__ adj, const unsigned short* __restrict__ Ht,
                        float* __restrict__ nbr) {
    __shared__ __align__(16) unsigned short As[128 * PADK];
    __shared__ __align__(16) unsigned short Bs[128 * PADK];
    const int tid = threadIdx.x;
    const int n0 = blockIdx.x * 128;
    const int i0 = blockIdx.y * 128;
    const int lane = tid & 63, w = tid >> 6;
    const int m = lane & 15, q = lane >> 4;
    const int wm = (w >> 1) * 64, wn = (w & 1) * 64;

    float4v acc[4][4];
#pragma unroll
    for (int r = 0; r < 4; ++r)
#pragma unroll
        for (int c = 0; c < 4; ++c) {
            float4v z = {0.f, 0.f, 0.f, 0.f};
            acc[r][c] = z;
        }

    const int si = tid & 127;   // staging row (i for A, n for B)
    const int kh = tid >> 7;    // 0/1 -> k-half

    for (int k0 = 0; k0 < NN; k0 += BKK) {
        __syncthreads();
        // ---- stage A: As[i][k] = (adj[k0+k][i0+i] > 0) ? bf16(1.0) : 0
        {
            const int* gp = adj + (size_t)(k0 + kh * 32) * NN + i0 + si;
            unsigned pk[16];
#pragma unroll
            for (int kk = 0; kk < 32; kk += 2) {
                int v0 = gp[(size_t)kk * NN];
                int v1 = gp[(size_t)(kk + 1) * NN];
                unsigned b0 = (v0 > 0) ? 0x3F80u : 0u;
                unsigned b1 = (v1 > 0) ? 0x3F80u : 0u;
                pk[kk >> 1] = b0 | (b1 << 16);
            }
            unsigned short* dst = &As[si * PADK + kh * 32];
#pragma unroll
            for (int qq = 0; qq < 4; ++qq) {
                int4 t;
                t.x = (int)pk[qq * 4 + 0]; t.y = (int)pk[qq * 4 + 1];
                t.z = (int)pk[qq * 4 + 2]; t.w = (int)pk[qq * 4 + 3];
                *(int4*)(dst + qq * 8) = t;
            }
        }
        // ---- stage B: Bs[n][k] = H_T[n0+n][k0+k]
        {
            const unsigned short* gp = Ht + (size_t)(n0 + si) * NN + k0 + kh * 32;
            unsigned short* dst = &Bs[si * PADK + kh * 32];
#pragma unroll
            for (int qq = 0; qq < 4; ++qq) {
                int4 t = *(const int4*)(gp + qq * 8);
                *(int4*)(dst + qq * 8) = t;
            }
        }
        __syncthreads();
#pragma unroll
        for (int ks = 0; ks < 2; ++ks) {
            short8 af[4], bfr[4];
#pragma unroll
            for (int r = 0; r < 4; ++r)
                af[r] = *(const short8*)&As[(wm + r * 16 + m) * PADK + ks * 32 + q * 8];
#pragma unroll
            for (int c = 0; c < 4; ++c)
                bfr[c] = *(const short8*)&Bs[(wn + c * 16 + m) * PADK + ks * 32 + q * 8];
#pragma unroll
            for (int r = 0; r < 4; ++r)
#pragma unroll
                for (int c = 0; c < 4; ++c)
                    acc[r][c] = __builtin_amdgcn_mfma_f32_16x16x32_bf16(af[r], bfr[c], acc[r][c], 0, 0, 0);
        }
    }

    // ---- epilogue: C/D layout col=lane&15, row=(lane>>4)*4+e
#pragma unroll
    for (int r = 0; r < 4; ++r) {
#pragma unroll
        for (int e = 0; e < 4; ++e) {
            int row = wm + r * 16 + q * 4 + e;
            float* dst = nbr + (size_t)(i0 + row) * NB + n0 + wn + m;
#pragma unroll
            for (int c = 0; c < 4; ++c) dst[c * 16] = acc[r][c][e];
        }
    }
}

// ---------------------------------------------------------------------------
// K3: s[bt,i] = sum_o h*a1 + nbr*a2 ; out[bt,i,o] = relu(s * sumh[bt,o])
// grid (NN/256, BT); thread -> node i (coalesced in i).
// ---------------------------------------------------------------------------
__launch_bounds__(256)
__global__ void k3_out(const unsigned short* __restrict__ Ht, const float* __restrict__ nbr,
                       const float* __restrict__ sumh, const void* __restrict__ a_raw,
                       void* __restrict__ out_raw, const unsigned* __restrict__ flagp) {
    const int i = blockIdx.x * 256 + threadIdx.x;
    const int bt = blockIdx.y;
    const bool isbf = (*flagp != 0u);

    float nv[32];
    const float* nr = nbr + (size_t)i * NB + bt * FOUT;
#pragma unroll
    for (int c = 0; c < 8; ++c) {
        float4 v = *(const float4*)(nr + c * 4);
        nv[c * 4 + 0] = v.x; nv[c * 4 + 1] = v.y; nv[c * 4 + 2] = v.z; nv[c * 4 + 3] = v.w;
    }

    float s = 0.f;
    if (isbf) {
        const unsigned short* ab = (const unsigned short*)a_raw;
#pragma unroll
        for (int o = 0; o < 32; ++o) {
            float h = bf2f(Ht[(size_t)(bt * FOUT + o) * NN + i]);
            float a1 = bf2f(ab[(size_t)o * NN + i]);
            float a2 = bf2f(ab[(size_t)(FOUT + o) * NN + i]);
            s += h * a1 + nv[o] * a2;
        }
    } else {
        const float* af = (const float*)a_raw;
#pragma unroll
        for (int o = 0; o < 32; ++o) {
            float h = bf2f(Ht[(size_t)(bt * FOUT + o) * NN + i]);
            float a1 = af[(size_t)o * NN + i];
            float a2 = af[(size_t)(FOUT + o) * NN + i];
            s += h * a1 + nv[o] * a2;
        }
    }

    float ov[32];
#pragma unroll
    for (int o = 0; o < 32; ++o) ov[o] = fmaxf(s * sumh[bt * FOUT + o], 0.f);

    size_t ob = ((size_t)bt * NN + i) * FOUT;
    if (isbf) {
        unsigned short* o16 = (unsigned short*)out_raw + ob;
#pragma unroll
        for (int c = 0; c < 8; ++c) {
            ushort4 p;
            p.x = f2bf(ov[c * 4 + 0]); p.y = f2bf(ov[c * 4 + 1]);
            p.z = f2bf(ov[c * 4 + 2]); p.w = f2bf(ov[c * 4 + 3]);
            *(ushort4*)(o16 + c * 4) = p;
        }
    } else {
        float* of = (float*)out_raw + ob;
#pragma unroll
        for (int c = 0; c < 8; ++c) {
            float4 v;
            v.x = ov[c * 4 + 0]; v.y = ov[c * 4 + 1]; v.z = ov[c * 4 + 2]; v.w = ov[c * 4 + 3];
            *(float4*)(of + c * 4) = v;
        }
    }
}

// ---------------------------------------------------------------------------
extern "C" void kernel_launch(void* const* d_in, const int* in_sizes, int n_in,
                              void* d_out, int out_size, void* d_ws, size_t ws_size,
                              hipStream_t stream) {
    const void* inp = d_in[0];
    const int* adj = (const int*)d_in[1];
    const void* W = d_in[2];
    const void* a = d_in[3];

    char* ws = (char*)d_ws;
    unsigned short* Ht = (unsigned short*)ws;                         // 8,388,608 B
    float* sumh = (float*)(ws + (size_t)8 * 1024 * 1024 + 0);         // 2,048 B (after Ht)
    // place sumh right after Ht, nbr after a 4 KB pad, flag at the end
    sumh = (float*)(ws + 8388608);
    float* nbr = (float*)(ws + 8388608 + 4096);                       // 16,777,216 B
    unsigned* flag = (unsigned*)(ws + 8388608 + 4096 + 16777216);

    sniff_dtype<<<1, 64, 0, stream>>>((const unsigned*)W, flag);
    k1_h<<<dim3(NN / 256, BT), 256, 0, stream>>>(inp, W, Ht, flag);
    k1b_sumh<<<NB, 256, 0, stream>>>(Ht, sumh);
    k2_gemm<<<dim3(NB / 128, NN / 128), 256, 0, stream>>>(adj, Ht, nbr);
    k3_out<<<dim3(NN / 256, BT), 256, 0, stream>>>(Ht, nbr, sumh, a, d_out, flag);
}

// Round 2
// 563.881 us; speedup vs baseline: 1.1115x; 1.1115x over previous
//
#include <hip/hip_runtime.h>

#define BT 16
#define NN 8192
#define FIN 128
#define FOUT 32
#define NB 512       // BT*FOUT
#define SPLITK 4
#define KSPAN (NN / SPLITK)   // 2048
#define BKK 64
#define PADK 72      // row stride 144 B = 9*16 B -> conflict-friendly b128

typedef __attribute__((ext_vector_type(8))) short short8;
typedef __attribute__((ext_vector_type(4))) float float4v;

__device__ __forceinline__ float bf2f(unsigned short u) {
    unsigned v = ((unsigned)u) << 16;
    float f;
    __builtin_memcpy(&f, &v, 4);
    return f;
}
__device__ __forceinline__ unsigned short f2bf(float f) {
    unsigned u;
    __builtin_memcpy(&u, &f, 4);
    u += 0x7FFFu + ((u >> 16) & 1u);   // RNE
    return (unsigned short)(u >> 16);
}

// ---------------------------------------------------------------------------
// Sniff: bf16-packed vs fp32 float tensors (worked in R1; keep).
// ---------------------------------------------------------------------------
__global__ void sniff_dtype(const unsigned* __restrict__ Wraw, unsigned* __restrict__ flag) {
    int lane = threadIdx.x;
    unsigned u = Wraw[lane];
    float f = bf2f((unsigned short)(u & 0xFFFFu));
    float af = fabsf(f);
    bool plaus = (af > 1e-5f) && (af < 1e3f);
    unsigned long long msk = __ballot(plaus);
    if (lane == 0) flag[0] = (__popcll(msk) >= 32) ? 1u : 0u;
}

// ---------------------------------------------------------------------------
// Zero: s2 [16][8192] f32 + sumh [512] f32 (contiguous; 129*256 float4 covers
// 132096 floats >= 131584 needed, slack is scratch).
// ---------------------------------------------------------------------------
__launch_bounds__(256)
__global__ void k_zero(float4* __restrict__ p) {
    float4 z; z.x = z.y = z.z = z.w = 0.f;
    p[(size_t)blockIdx.x * 256 + threadIdx.x] = z;
}

// ---------------------------------------------------------------------------
// K0: pack adj -> P[w][i] bits, w = k/32, bit b = (adj[w*32+b][i] > 0).
// Reads adj exactly once (coalesced 256 B/wave rows); writes 8 MB coalesced.
// grid (32 i-tiles of 256, 32 k-tiles of 256), 256 thr.
// ---------------------------------------------------------------------------
__launch_bounds__(256)
__global__ void k0_pack(const int* __restrict__ adj, unsigned* __restrict__ P) {
    const int i = blockIdx.x * 256 + threadIdx.x;
    const int k0 = blockIdx.y * 256;
    const int w0 = k0 >> 5;
    unsigned words[8];
#pragma unroll
    for (int wk = 0; wk < 8; ++wk) {
        unsigned wv = 0;
        const int* gp = adj + (size_t)(k0 + wk * 32) * NN + i;
#pragma unroll
        for (int kk = 0; kk < 32; ++kk)
            wv |= (gp[(size_t)kk * NN] > 0 ? 1u : 0u) << kk;
        words[wk] = wv;
    }
#pragma unroll
    for (int wk = 0; wk < 8; ++wk)
        P[(size_t)(w0 + wk) * NN + i] = words[wk];
}

// ---------------------------------------------------------------------------
// K1: h = inp @ W via MFMA -> Ht bf16 [NB][NN]; fused sumh row-sums (atomic).
// A = W^T (LDS, bf16, pad 136), B = inp rows loaded straight from global.
// grid (64 j-tiles of 128, BT), 256 thr = 4 waves; wave: o-16 x j-64.
// ---------------------------------------------------------------------------
__launch_bounds__(256)
__global__ void k1_h(const void* __restrict__ inp_raw, const void* __restrict__ W_raw,
                     unsigned short* __restrict__ Ht, float* __restrict__ sumh,
                     const unsigned* __restrict__ flagp) {
    __shared__ __align__(16) unsigned short Wt[32 * 136];
    const int tid = threadIdx.x;
    const int bt = blockIdx.y;
    const int j0 = blockIdx.x * 128;
    const bool isbf = (*flagp != 0u);

    if (isbf) {
        const unsigned short* Wb = (const unsigned short*)W_raw;
#pragma unroll
        for (int r = 0; r < 16; ++r) {
            int idx = tid + 256 * r, i = idx >> 5, o = idx & 31;
            Wt[o * 136 + i] = Wb[idx];
        }
    } else {
        const float* Wf = (const float*)W_raw;
#pragma unroll
        for (int r = 0; r < 16; ++r) {
            int idx = tid + 256 * r, i = idx >> 5, o = idx & 31;
            Wt[o * 136 + i] = f2bf(Wf[idx]);
        }
    }
    __syncthreads();

    const int lane = tid & 63, w = tid >> 6;
    const int m = lane & 15, q = lane >> 4;
    const int mt = (w & 1) * 16;        // o offset
    const int nt = (w >> 1) * 64;       // j offset

    float4v acc[4];
#pragma unroll
    for (int c = 0; c < 4; ++c) { float4v z = {0.f, 0.f, 0.f, 0.f}; acc[c] = z; }

#pragma unroll
    for (int kstep = 0; kstep < 4; ++kstep) {
        short8 af = *(const short8*)&Wt[(mt + m) * 136 + kstep * 32 + q * 8];
#pragma unroll
        for (int c = 0; c < 4; ++c) {
            int j = j0 + nt + c * 16 + m;
            short8 bfrag;
            if (isbf) {
                bfrag = *(const short8*)((const unsigned short*)inp_raw +
                        ((size_t)bt * NN + j) * FIN + kstep * 32 + q * 8);
            } else {
                const float* fp = (const float*)inp_raw + ((size_t)bt * NN + j) * FIN + kstep * 32 + q * 8;
                float4 f0 = *(const float4*)fp;
                float4 f1 = *(const float4*)(fp + 4);
                union { unsigned short u[8]; short8 v; } t;
                t.u[0] = f2bf(f0.x); t.u[1] = f2bf(f0.y); t.u[2] = f2bf(f0.z); t.u[3] = f2bf(f0.w);
                t.u[4] = f2bf(f1.x); t.u[5] = f2bf(f1.y); t.u[6] = f2bf(f1.z); t.u[7] = f2bf(f1.w);
                bfrag = t.v;
            }
            acc[c] = __builtin_amdgcn_mfma_f32_16x16x32_bf16(af, bfrag, acc[c], 0, 0, 0);
        }
    }

    // store Ht (C layout: col=lane&15 -> j, row=q*4+e -> o)
#pragma unroll
    for (int c = 0; c < 4; ++c) {
#pragma unroll
        for (int e = 0; e < 4; ++e) {
            int o = mt + q * 4 + e;
            int j = j0 + nt + c * 16 + m;
            Ht[(size_t)(bt * FOUT + o) * NN + j] = f2bf(acc[c][e]);
        }
    }
    // fused sumh partials: sum over this wave's 64 j per o-row
#pragma unroll
    for (int e = 0; e < 4; ++e) {
        float s = acc[0][e] + acc[1][e] + acc[2][e] + acc[3][e];
        s += __shfl_xor(s, 1); s += __shfl_xor(s, 2);
        s += __shfl_xor(s, 4); s += __shfl_xor(s, 8);
        if (m == 0) atomicAdd(&sumh[bt * FOUT + mt + q * 4 + e], s);
    }
}

// ---------------------------------------------------------------------------
// K2: s2[bt][i] += sum_o a2[i][o] * (sum_k mask[k][i] * Ht[bt*32+o][k])
// MFMA GEMM 128(i) x 128(bto) x BK=64, split-K=4, A expanded from bitmask P,
// epilogue folds the a2 dot + cross-lane reduce + atomic (nbr never stored).
// grid (4 n-tiles, 64 i-tiles, SPLITK), 256 thr (4 waves, 64x64 each).
// ---------------------------------------------------------------------------
__launch_bounds__(256)
__global__ void k2_gemm(const unsigned* __restrict__ P, const unsigned short* __restrict__ Ht,
                        const void* __restrict__ a_raw, float* __restrict__ s2,
                        const unsigned* __restrict__ flagp) {
    __shared__ __align__(16) unsigned short As[128 * PADK];
    __shared__ __align__(16) unsigned short Bs[128 * PADK];
    const int tid = threadIdx.x;
    const int n0 = blockIdx.x * 128;
    const int i0 = blockIdx.y * 128;
    const int z = blockIdx.z;
    const int lane = tid & 63, w = tid >> 6;
    const int m = lane & 15, q = lane >> 4;
    const int wm = (w >> 1) * 64, wn = (w & 1) * 64;

    float4v acc[4][4];
#pragma unroll
    for (int r = 0; r < 4; ++r)
#pragma unroll
        for (int c = 0; c < 4; ++c) { float4v zz = {0.f, 0.f, 0.f, 0.f}; acc[r][c] = zz; }

    const int si = tid & 127;
    const int kh = tid >> 7;

    for (int ks0 = 0; ks0 < KSPAN; ks0 += BKK) {
        const int k0 = z * KSPAN + ks0;
        __syncthreads();
        // ---- stage A: expand 32 bits -> 32 bf16 (1.0/0.0)
        {
            unsigned word = P[(size_t)((k0 >> 5) + kh) * NN + i0 + si];
            unsigned pk[16];
#pragma unroll
            for (int p = 0; p < 16; ++p) {
                unsigned b0 = (word >> (2 * p)) & 1u;
                unsigned b1 = (word >> (2 * p + 1)) & 1u;
                pk[p] = (b0 ? 0x3F80u : 0u) | (b1 ? 0x3F800000u : 0u);
            }
            unsigned short* dst = &As[si * PADK + kh * 32];
#pragma unroll
            for (int qq = 0; qq < 4; ++qq) {
                int4 t;
                t.x = (int)pk[qq * 4 + 0]; t.y = (int)pk[qq * 4 + 1];
                t.z = (int)pk[qq * 4 + 2]; t.w = (int)pk[qq * 4 + 3];
                *(int4*)(dst + qq * 8) = t;
            }
        }
        // ---- stage B from Ht
        {
            const unsigned short* gp = Ht + (size_t)(n0 + si) * NN + k0 + kh * 32;
            unsigned short* dst = &Bs[si * PADK + kh * 32];
#pragma unroll
            for (int qq = 0; qq < 4; ++qq) {
                int4 t = *(const int4*)(gp + qq * 8);
                *(int4*)(dst + qq * 8) = t;
            }
        }
        __syncthreads();
#pragma unroll
        for (int ks = 0; ks < 2; ++ks) {
            short8 af[4], bfr[4];
#pragma unroll
            for (int r = 0; r < 4; ++r)
                af[r] = *(const short8*)&As[(wm + r * 16 + m) * PADK + ks * 32 + q * 8];
#pragma unroll
            for (int c = 0; c < 4; ++c)
                bfr[c] = *(const short8*)&Bs[(wn + c * 16 + m) * PADK + ks * 32 + q * 8];
#pragma unroll
            for (int r = 0; r < 4; ++r)
#pragma unroll
                for (int c = 0; c < 4; ++c)
                    acc[r][c] = __builtin_amdgcn_mfma_f32_16x16x32_bf16(af[r], bfr[c], acc[r][c], 0, 0, 0);
        }
    }

    // ---- fused epilogue: s2 partial = sum_o nbr*a2, reduced across m-lanes
    const bool isbf = (*flagp != 0u);
    const int btA = (n0 + wn) >> 5;     // cols wn..wn+31 -> btA; +32..63 -> btA+1
#pragma unroll
    for (int r = 0; r < 4; ++r) {
#pragma unroll
        for (int e = 0; e < 4; ++e) {
            int gi = i0 + wm + r * 16 + q * 4 + e;
            float a2m, a2m16;
            if (isbf) {
                const unsigned short* ab = (const unsigned short*)a_raw;
                a2m   = bf2f(ab[(size_t)(FOUT + m) * NN + gi]);
                a2m16 = bf2f(ab[(size_t)(FOUT + 16 + m) * NN + gi]);
            } else {
                const float* afp = (const float*)a_raw;
                a2m   = afp[(size_t)(FOUT + m) * NN + gi];
                a2m16 = afp[(size_t)(FOUT + 16 + m) * NN + gi];
            }
            float sA = acc[r][0][e] * a2m + acc[r][1][e] * a2m16;
            float sB = acc[r][2][e] * a2m + acc[r][3][e] * a2m16;
            sA += __shfl_xor(sA, 1); sA += __shfl_xor(sA, 2);
            sA += __shfl_xor(sA, 4); sA += __shfl_xor(sA, 8);
            sB += __shfl_xor(sB, 1); sB += __shfl_xor(sB, 2);
            sB += __shfl_xor(sB, 4); sB += __shfl_xor(sB, 8);
            if (m == 0) {
                atomicAdd(&s2[(size_t)btA * NN + gi], sA);
                atomicAdd(&s2[(size_t)(btA + 1) * NN + gi], sB);
            }
        }
    }
}

// ---------------------------------------------------------------------------
// K3: s = s2 + sum_o h*a1 ; out = relu(s * sumh[bt,:])
// ---------------------------------------------------------------------------
__launch_bounds__(256)
__global__ void k3_out(const unsigned short* __restrict__ Ht, const float* __restrict__ s2,
                       const float* __restrict__ sumh, const void* __restrict__ a_raw,
                       void* __restrict__ out_raw, const unsigned* __restrict__ flagp) {
    const int i = blockIdx.x * 256 + threadIdx.x;
    const int bt = blockIdx.y;
    const bool isbf = (*flagp != 0u);

    float s = s2[(size_t)bt * NN + i];
    if (isbf) {
        const unsigned short* ab = (const unsigned short*)a_raw;
#pragma unroll
        for (int o = 0; o < 32; ++o) {
            float h = bf2f(Ht[(size_t)(bt * FOUT + o) * NN + i]);
            float a1 = bf2f(ab[(size_t)o * NN + i]);
            s += h * a1;
        }
    } else {
        const float* afp = (const float*)a_raw;
#pragma unroll
        for (int o = 0; o < 32; ++o) {
            float h = bf2f(Ht[(size_t)(bt * FOUT + o) * NN + i]);
            s += h * afp[(size_t)o * NN + i];
        }
    }

    float ov[32];
#pragma unroll
    for (int o = 0; o < 32; ++o) ov[o] = fmaxf(s * sumh[bt * FOUT + o], 0.f);

    size_t ob = ((size_t)bt * NN + i) * FOUT;
    if (isbf) {
        unsigned short* o16 = (unsigned short*)out_raw + ob;
#pragma unroll
        for (int c = 0; c < 8; ++c) {
            ushort4 p;
            p.x = f2bf(ov[c * 4 + 0]); p.y = f2bf(ov[c * 4 + 1]);
            p.z = f2bf(ov[c * 4 + 2]); p.w = f2bf(ov[c * 4 + 3]);
            *(ushort4*)(o16 + c * 4) = p;
        }
    } else {
        float* of = (float*)out_raw + ob;
#pragma unroll
        for (int c = 0; c < 8; ++c) {
            float4 v;
            v.x = ov[c * 4 + 0]; v.y = ov[c * 4 + 1]; v.z = ov[c * 4 + 2]; v.w = ov[c * 4 + 3];
            *(float4*)(of + c * 4) = v;
        }
    }
}

// ---------------------------------------------------------------------------
extern "C" void kernel_launch(void* const* d_in, const int* in_sizes, int n_in,
                              void* d_out, int out_size, void* d_ws, size_t ws_size,
                              hipStream_t stream) {
    const void* inp = d_in[0];
    const int* adj = (const int*)d_in[1];
    const void* W = d_in[2];
    const void* a = d_in[3];

    char* ws = (char*)d_ws;
    unsigned short* Ht = (unsigned short*)ws;                    // 8 MB
    unsigned* P = (unsigned*)(ws + 8388608);                     // 8 MB
    unsigned* flag = (unsigned*)(ws + 16777216);                 // 4 B
    float* s2 = (float*)(ws + 16781312);                         // 512 KB
    float* sumh = (float*)(ws + 16781312 + 524288);              // 2 KB

    sniff_dtype<<<1, 64, 0, stream>>>((const unsigned*)W, flag);
    k_zero<<<129, 256, 0, stream>>>((float4*)s2);                // zeros s2 + sumh (+slack)
    k0_pack<<<dim3(32, 32), 256, 0, stream>>>(adj, P);
    k1_h<<<dim3(NN / 128, BT), 256, 0, stream>>>(inp, W, Ht, sumh, flag);
    k2_gemm<<<dim3(NB / 128, NN / 128, SPLITK), 256, 0, stream>>>(P, Ht, a, s2, flag);
    k3_out<<<dim3(NN / 256, BT), 256, 0, stream>>>(Ht, s2, sumh, a, d_out, flag);
}

// Round 3
// 503.010 us; speedup vs baseline: 1.2460x; 1.1210x over previous
//
#include <hip/hip_runtime.h>

#define BT 16
#define NN 8192
#define FIN 128
#define FOUT 32
#define NB 512       // BT*FOUT
#define SPLITK 4
#define KSPAN (NN / SPLITK)   // 2048
#define BKK 64
#define PADK 72      // As row stride: 144 B -> octet-conflict-free for write+read

typedef __attribute__((ext_vector_type(8))) short short8;
typedef __attribute__((ext_vector_type(4))) float float4v;

__device__ __forceinline__ float bf2f(unsigned short u) {
    unsigned v = ((unsigned)u) << 16;
    float f;
    __builtin_memcpy(&f, &v, 4);
    return f;
}
__device__ __forceinline__ unsigned short f2bf(float f) {
    unsigned u;
    __builtin_memcpy(&u, &f, 4);
    u += 0x7FFFu + ((u >> 16) & 1u);   // RNE
    return (unsigned short)(u >> 16);
}

// async global->LDS, 16 B per lane; LDS dest = wave-uniform base + lane*16
__device__ __forceinline__ void load_lds16(const unsigned short* g, unsigned short* l) {
    __builtin_amdgcn_global_load_lds((const __attribute__((address_space(1))) void*)g,
                                     (__attribute__((address_space(3))) void*)l, 16, 0, 0);
}

// ---------------------------------------------------------------------------
// Sniff bf16-vs-fp32 (proven R1/R2) + zero sumh[512].
// ---------------------------------------------------------------------------
__global__ void sniff_dtype(const unsigned* __restrict__ Wraw, unsigned* __restrict__ flag,
                            float* __restrict__ sumh) {
    int lane = threadIdx.x;
    unsigned u = Wraw[lane];
    float f = bf2f((unsigned short)(u & 0xFFFFu));
    float af = fabsf(f);
    bool plaus = (af > 1e-5f) && (af < 1e3f);
    unsigned long long msk = __ballot(plaus);
    if (lane == 0) flag[0] = (__popcll(msk) >= 32) ? 1u : 0u;
#pragma unroll
    for (int r = 0; r < 8; ++r) sumh[lane + 64 * r] = 0.f;
}

// ---------------------------------------------------------------------------
// K01 fused: [0,128) zero s2 | [128,1152) pack adj->P bits | [1152,2176) h=inp@W
// Pack (HBM-bound, 256 MB) co-schedules with the MFMA h-compute.
// ---------------------------------------------------------------------------
__launch_bounds__(256)
__global__ void k01(const int* __restrict__ adj, unsigned* __restrict__ P,
                    const void* __restrict__ inp_raw, const void* __restrict__ W_raw,
                    unsigned short* __restrict__ Ht, float* __restrict__ sumh,
                    float4* __restrict__ s2v, const unsigned* __restrict__ flagp) {
    __shared__ __align__(16) unsigned short Wt[32 * 136];
    int bid = blockIdx.x;
    const int tid = threadIdx.x;

    if (bid < 128) {                 // ---- zero s2 (131072 floats = 32768 float4)
        float4 z; z.x = z.y = z.z = z.w = 0.f;
        s2v[bid * 256 + tid] = z;
        return;
    }
    bid -= 128;
    if (bid < 1024) {                // ---- pack: P[w][i] bit b = adj[w*32+b][i] > 0
        const int i = (bid & 31) * 256 + tid;
        const int k0 = (bid >> 5) * 256;
        const int w0 = k0 >> 5;
        unsigned words[8];
#pragma unroll
        for (int wk = 0; wk < 8; ++wk) {
            unsigned wv = 0;
            const int* gp = adj + (size_t)(k0 + wk * 32) * NN + i;
#pragma unroll
            for (int kk = 0; kk < 32; ++kk)
                wv |= (gp[(size_t)kk * NN] > 0 ? 1u : 0u) << kk;
            words[wk] = wv;
        }
#pragma unroll
        for (int wk = 0; wk < 8; ++wk)
            P[(size_t)(w0 + wk) * NN + i] = words[wk];
        return;
    }
    bid -= 1024;                     // ---- h-part (R2 k1 body, proven)
    const int bt = bid >> 6;
    const int j0 = (bid & 63) * 128;
    const bool isbf = (*flagp != 0u);

    if (isbf) {
        const unsigned short* Wb = (const unsigned short*)W_raw;
#pragma unroll
        for (int r = 0; r < 16; ++r) {
            int idx = tid + 256 * r, i = idx >> 5, o = idx & 31;
            Wt[o * 136 + i] = Wb[idx];
        }
    } else {
        const float* Wf = (const float*)W_raw;
#pragma unroll
        for (int r = 0; r < 16; ++r) {
            int idx = tid + 256 * r, i = idx >> 5, o = idx & 31;
            Wt[o * 136 + i] = f2bf(Wf[idx]);
        }
    }
    __syncthreads();

    const int lane = tid & 63, w = tid >> 6;
    const int m = lane & 15, q = lane >> 4;
    const int mt = (w & 1) * 16;
    const int nt = (w >> 1) * 64;

    float4v acc[4];
#pragma unroll
    for (int c = 0; c < 4; ++c) { float4v z = {0.f, 0.f, 0.f, 0.f}; acc[c] = z; }

#pragma unroll
    for (int kstep = 0; kstep < 4; ++kstep) {
        short8 af = *(const short8*)&Wt[(mt + m) * 136 + kstep * 32 + q * 8];
#pragma unroll
        for (int c = 0; c < 4; ++c) {
            int j = j0 + nt + c * 16 + m;
            short8 bfrag;
            if (isbf) {
                bfrag = *(const short8*)((const unsigned short*)inp_raw +
                        ((size_t)bt * NN + j) * FIN + kstep * 32 + q * 8);
            } else {
                const float* fp = (const float*)inp_raw + ((size_t)bt * NN + j) * FIN + kstep * 32 + q * 8;
                float4 f0 = *(const float4*)fp;
                float4 f1 = *(const float4*)(fp + 4);
                union { unsigned short u[8]; short8 v; } t;
                t.u[0] = f2bf(f0.x); t.u[1] = f2bf(f0.y); t.u[2] = f2bf(f0.z); t.u[3] = f2bf(f0.w);
                t.u[4] = f2bf(f1.x); t.u[5] = f2bf(f1.y); t.u[6] = f2bf(f1.z); t.u[7] = f2bf(f1.w);
                bfrag = t.v;
            }
            acc[c] = __builtin_amdgcn_mfma_f32_16x16x32_bf16(af, bfrag, acc[c], 0, 0, 0);
        }
    }

#pragma unroll
    for (int c = 0; c < 4; ++c) {
#pragma unroll
        for (int e = 0; e < 4; ++e) {
            int o = mt + q * 4 + e;
            int j = j0 + nt + c * 16 + m;
            Ht[(size_t)(bt * FOUT + o) * NN + j] = f2bf(acc[c][e]);
        }
    }
#pragma unroll
    for (int e = 0; e < 4; ++e) {
        float s = acc[0][e] + acc[1][e] + acc[2][e] + acc[3][e];
        s += __shfl_xor(s, 1); s += __shfl_xor(s, 2);
        s += __shfl_xor(s, 4); s += __shfl_xor(s, 8);
        if (m == 0) atomicAdd(&sumh[bt * FOUT + mt + q * 4 + e], s);
    }
}

// ---------------------------------------------------------------------------
// K2: s2[bt][i] += sum_o a2[i,o] * (sum_k mask[k,i] * Ht[bt*32+o][k])
// 128(i) x 128(n=bto) x BK=64, split-K=4. B staged via global_load_lds x16
// with XOR source-swizzle (kb_src = kb ^ (n&7), LDS unpadded) -> coalesced DMA
// AND conflict-free ds_read_b128. A expanded from bitmask into padded As.
// ---------------------------------------------------------------------------
__launch_bounds__(256, 4)
__global__ void k2_gemm(const unsigned* __restrict__ P, const unsigned short* __restrict__ Ht,
                        const void* __restrict__ a_raw, float* __restrict__ s2,
                        const unsigned* __restrict__ flagp) {
    __shared__ __align__(16) unsigned short As[128 * PADK];  // 18.4 KB
    __shared__ __align__(16) unsigned short Bs[128 * 64];    // 16 KB
    const int tid = threadIdx.x;
    const int n0 = blockIdx.x * 128;
    const int i0 = blockIdx.y * 128;
    const int z = blockIdx.z;
    const int lane = tid & 63, w = tid >> 6;
    const int m = lane & 15, q = lane >> 4;
    const int wm = (w >> 1) * 64, wn = (w & 1) * 64;

    // per-lane DMA source offsets for the 4 calls (16 B each): unit u covers
    // LDS slot (n = u>>3, kb = u&7); source column block kb ^ (n&7).
    int boff[4];
#pragma unroll
    for (int c = 0; c < 4; ++c) {
        int u = (w * 4 + c) * 64 + lane;
        int n = u >> 3;
        int kbs = (u & 7) ^ (n & 7);
        boff[c] = (n0 + n) * NN + kbs * 8;
    }

    float4v acc[4][4];
#pragma unroll
    for (int r = 0; r < 4; ++r)
#pragma unroll
        for (int c = 0; c < 4; ++c) { float4v zz = {0.f, 0.f, 0.f, 0.f}; acc[r][c] = zz; }

    const int si = tid & 127;
    const int kh = tid >> 7;
    const unsigned* Prow = P + (size_t)((z * KSPAN) >> 5) * NN + i0 + si + (size_t)kh * NN;

    for (int ks0 = 0; ks0 < KSPAN; ks0 += BKK) {
        const int k0 = z * KSPAN + ks0;
        __syncthreads();
        // ---- B: 4 DMA calls/wave, LDS dest wave-uniform base + lane*16
#pragma unroll
        for (int c = 0; c < 4; ++c)
            load_lds16(Ht + boff[c] + k0, &Bs[(w * 4 + c) * 512]);
        // ---- A: expand 32 bits -> 32 bf16 into padded As
        {
            unsigned word = Prow[(size_t)(ks0 >> 5) * NN];
            unsigned pk[16];
#pragma unroll
            for (int p = 0; p < 16; ++p) {
                unsigned b0 = (word >> (2 * p)) & 1u;
                unsigned b1 = (word >> (2 * p + 1)) & 1u;
                pk[p] = (b0 ? 0x3F80u : 0u) | (b1 ? 0x3F800000u : 0u);
            }
            unsigned short* dst = &As[si * PADK + kh * 32];
#pragma unroll
            for (int qq = 0; qq < 4; ++qq) {
                int4 t;
                t.x = (int)pk[qq * 4 + 0]; t.y = (int)pk[qq * 4 + 1];
                t.z = (int)pk[qq * 4 + 2]; t.w = (int)pk[qq * 4 + 3];
                *(int4*)(dst + qq * 8) = t;
            }
        }
        __syncthreads();
#pragma unroll
        for (int ks = 0; ks < 2; ++ks) {
            short8 af[4], bfr[4];
#pragma unroll
            for (int r = 0; r < 4; ++r)
                af[r] = *(const short8*)&As[(wm + r * 16 + m) * PADK + ks * 32 + q * 8];
#pragma unroll
            for (int c = 0; c < 4; ++c) {
                int row = wn + c * 16 + m;
                int kbs = (ks * 4 + q) ^ (m & 7);   // row&7 == m&7 (wn,c*16 are mult of 8... 16)
                bfr[c] = *(const short8*)&Bs[row * 64 + kbs * 8];
            }
#pragma unroll
            for (int r = 0; r < 4; ++r)
#pragma unroll
                for (int c = 0; c < 4; ++c)
                    acc[r][c] = __builtin_amdgcn_mfma_f32_16x16x32_bf16(af[r], bfr[c], acc[r][c], 0, 0, 0);
        }
    }

    // ---- fused epilogue: s2 partial = sum_o nbr*a2, m-lane reduce, atomic
    const bool isbf = (*flagp != 0u);
    const int btA = (n0 + wn) >> 5;
#pragma unroll
    for (int r = 0; r < 4; ++r) {
#pragma unroll
        for (int e = 0; e < 4; ++e) {
            int gi = i0 + wm + r * 16 + q * 4 + e;
            float a2m, a2m16;
            if (isbf) {
                const unsigned short* ab = (const unsigned short*)a_raw;
                a2m   = bf2f(ab[(size_t)(FOUT + m) * NN + gi]);
                a2m16 = bf2f(ab[(size_t)(FOUT + 16 + m) * NN + gi]);
            } else {
                const float* afp = (const float*)a_raw;
                a2m   = afp[(size_t)(FOUT + m) * NN + gi];
                a2m16 = afp[(size_t)(FOUT + 16 + m) * NN + gi];
            }
            float sA = acc[r][0][e] * a2m + acc[r][1][e] * a2m16;
            float sB = acc[r][2][e] * a2m + acc[r][3][e] * a2m16;
            sA += __shfl_xor(sA, 1); sA += __shfl_xor(sA, 2);
            sA += __shfl_xor(sA, 4); sA += __shfl_xor(sA, 8);
            sB += __shfl_xor(sB, 1); sB += __shfl_xor(sB, 2);
            sB += __shfl_xor(sB, 4); sB += __shfl_xor(sB, 8);
            if (m == 0) {
                atomicAdd(&s2[(size_t)btA * NN + gi], sA);
                atomicAdd(&s2[(size_t)(btA + 1) * NN + gi], sB);
            }
        }
    }
}

// ---------------------------------------------------------------------------
// K3: s = s2 + sum_o h*a1 ; out = relu(s * sumh[bt,:])
// ---------------------------------------------------------------------------
__launch_bounds__(256)
__global__ void k3_out(const unsigned short* __restrict__ Ht, const float* __restrict__ s2,
                       const float* __restrict__ sumh, const void* __restrict__ a_raw,
                       void* __restrict__ out_raw, const unsigned* __restrict__ flagp) {
    const int i = blockIdx.x * 256 + threadIdx.x;
    const int bt = blockIdx.y;
    const bool isbf = (*flagp != 0u);

    float s = s2[(size_t)bt * NN + i];
    if (isbf) {
        const unsigned short* ab = (const unsigned short*)a_raw;
#pragma unroll
        for (int o = 0; o < 32; ++o) {
            float h = bf2f(Ht[(size_t)(bt * FOUT + o) * NN + i]);
            s += h * bf2f(ab[(size_t)o * NN + i]);
        }
    } else {
        const float* afp = (const float*)a_raw;
#pragma unroll
        for (int o = 0; o < 32; ++o) {
            float h = bf2f(Ht[(size_t)(bt * FOUT + o) * NN + i]);
            s += h * afp[(size_t)o * NN + i];
        }
    }

    float ov[32];
#pragma unroll
    for (int o = 0; o < 32; ++o) ov[o] = fmaxf(s * sumh[bt * FOUT + o], 0.f);

    size_t ob = ((size_t)bt * NN + i) * FOUT;
    if (isbf) {
        unsigned short* o16 = (unsigned short*)out_raw + ob;
#pragma unroll
        for (int c = 0; c < 8; ++c) {
            ushort4 p;
            p.x = f2bf(ov[c * 4 + 0]); p.y = f2bf(ov[c * 4 + 1]);
            p.z = f2bf(ov[c * 4 + 2]); p.w = f2bf(ov[c * 4 + 3]);
            *(ushort4*)(o16 + c * 4) = p;
        }
    } else {
        float* of = (float*)out_raw + ob;
#pragma unroll
        for (int c = 0; c < 8; ++c) {
            float4 v;
            v.x = ov[c * 4 + 0]; v.y = ov[c * 4 + 1]; v.z = ov[c * 4 + 2]; v.w = ov[c * 4 + 3];
            *(float4*)(of + c * 4) = v;
        }
    }
}

// ---------------------------------------------------------------------------
extern "C" void kernel_launch(void* const* d_in, const int* in_sizes, int n_in,
                              void* d_out, int out_size, void* d_ws, size_t ws_size,
                              hipStream_t stream) {
    const void* inp = d_in[0];
    const int* adj = (const int*)d_in[1];
    const void* W = d_in[2];
    const void* a = d_in[3];

    char* ws = (char*)d_ws;
    unsigned short* Ht = (unsigned short*)ws;                    // 8 MB
    unsigned* P = (unsigned*)(ws + 8388608);                     // 8 MB
    unsigned* flag = (unsigned*)(ws + 16777216);                 // 4 B
    float* s2 = (float*)(ws + 16781312);                         // 512 KB (16B aligned)
    float* sumh = (float*)(ws + 16781312 + 524288);              // 2 KB

    sniff_dtype<<<1, 64, 0, stream>>>((const unsigned*)W, flag, sumh);
    k01<<<2176, 256, 0, stream>>>(adj, P, inp, W, Ht, sumh, (float4*)s2, flag);
    k2_gemm<<<dim3(NB / 128, NN / 128, SPLITK), 256, 0, stream>>>(P, Ht, a, s2, flag);
    k3_out<<<dim3(NN / 256, BT), 256, 0, stream>>>(Ht, s2, sumh, a, d_out, flag);
}